// Round 7
// baseline (1922.282 us; speedup 1.0000x reference)
//
#include <hip/hip_runtime.h>

#define N_PTS   4096
#define N_BATCH 16
#define BLOCK   1024               // 16 waves: all share one A-stream (L1 dedup)
#define INV_CNT (1.0f / (2.0f * N_BATCH * N_PTS))

typedef _Float16 f16x8  __attribute__((ext_vector_type(8)));
typedef float    f32x16 __attribute__((ext_vector_type(16)));

// 32x32x16 f16 MFMA, K-slot packing (split o = oh + ol, p = ph + pl in f16):
//   A-row (opposite point o), 16 halves (32 B):
//     [0..7]  = -2oh_x,-2oh_y,-2oh_z, -2ol_x,-2ol_y,-2ol_z, -2oh_x,-2oh_y
//     [8..15] = -2oh_z, o2h, o2l, 0,0,0,0,0         (o2 = |o|^2 hi/lo split)
//   B-col (query p):
//     [0..7]  = ph_x,ph_y,ph_z, ph_x,ph_y,ph_z, pl_x,pl_y
//     [8..15] = pl_z, 1, 1, 0,0,0,0,0
//   => C = o2 - 2 o.p  (dropped ol.pl ~2^-22; verified R5/R6, absmax 0.0)
// A lane layout: row=l&31, k=(l>>5)*8+j -> one contiguous 16B load per lane.
// C layout: col=l&31; 16 regs + lane-half cover all 32 rows.
__global__ __launch_bounds__(256) void prep_kernel(
    const float* __restrict__ tpl, const float* __restrict__ src,
    _Float16* __restrict__ arow, float* __restrict__ out) {
    int pt = blockIdx.x * 256 + threadIdx.x;          // 0..131071 (T set, then S set)
    if (pt == 0) out[0] = 0.0f;                       // main runs after (stream order)
    const float* p = (pt < 65536 ? tpl : src) + (size_t)(pt & 65535) * 3;
    float x = p[0], y = p[1], z = p[2];
    float o2 = fmaf(x, x, fmaf(y, y, z * z));
    _Float16 xh = (_Float16)x, yh = (_Float16)y, zh = (_Float16)z;
    _Float16 xl = (_Float16)(x - (float)xh);
    _Float16 yl = (_Float16)(y - (float)yh);
    _Float16 zl = (_Float16)(z - (float)zh);
    _Float16 o2h = (_Float16)o2;
    _Float16 o2l = (_Float16)(o2 - (float)o2h);
    const _Float16 m2 = (_Float16)-2.0f;              // exact power-of-2 scale
    f16x8 v0, v1;
    v0[0] = m2 * xh; v0[1] = m2 * yh; v0[2] = m2 * zh;
    v0[3] = m2 * xl; v0[4] = m2 * yl; v0[5] = m2 * zl;
    v0[6] = m2 * xh; v0[7] = m2 * yh;
    v1[0] = m2 * zh; v1[1] = o2h; v1[2] = o2l;
    v1[3] = (_Float16)0.0f; v1[4] = (_Float16)0.0f; v1[5] = (_Float16)0.0f;
    v1[6] = (_Float16)0.0f; v1[7] = (_Float16)0.0f;
    *(f16x8*)(arow + (size_t)pt * 16)     = v0;
    *(f16x8*)(arow + (size_t)pt * 16 + 8) = v1;
}

// Grid (8, 16, 2) = 256 blocks x 16 waves = 16 waves/CU = 4/SIMD.
// Wave owns 32 queries (1 B-frag); streams 128 A-tiles with a depth-4
// prefetch ring; fold uses 2 independent min3 chains of depth 4.
__global__ __launch_bounds__(BLOCK, 4) void chamfer_mfma(
    const float* __restrict__ tpl, const float* __restrict__ src,
    const _Float16* __restrict__ arow, float* __restrict__ out) {
    __shared__ float wsum[BLOCK / 64];

    const int tid = threadIdx.x;
    const int wv = tid >> 6, lane = tid & 63;
    const int n = lane & 31, g = lane >> 5;           // B col / K-half group
    const int qb = blockIdx.x, batch = blockIdx.y, dir = blockIdx.z;

    const float* qpts = (dir == 0) ? src : tpl;       // dist1: query = source
    const _Float16* abase = arow + ((dir == 0) ? (size_t)0 : (size_t)65536 * 16)
                          + (size_t)batch * 4096 * 16;

    // Build B fragment + |p|^2 (lane n -> query qb*512 + wv*32 + n).
    const int q = qb * 512 + wv * 32 + n;
    const float* p = qpts + (size_t)(batch * 4096 + q) * 3;
    float px = p[0], py = p[1], pz = p[2];
    float p2 = fmaf(px, px, fmaf(py, py, pz * pz));
    f16x8 bf;
    {
        _Float16 xh = (_Float16)px, yh = (_Float16)py, zh = (_Float16)pz;
        _Float16 xl = (_Float16)(px - (float)xh);
        _Float16 yl = (_Float16)(py - (float)yh);
        _Float16 zl = (_Float16)(pz - (float)zh);
        if (g == 0) {
            bf[0] = xh; bf[1] = yh; bf[2] = zh;
            bf[3] = xh; bf[4] = yh; bf[5] = zh;
            bf[6] = xl; bf[7] = yl;
        } else {
            bf[0] = zl; bf[1] = (_Float16)1.0f; bf[2] = (_Float16)1.0f;
            bf[3] = (_Float16)0.0f; bf[4] = (_Float16)0.0f; bf[5] = (_Float16)0.0f;
            bf[6] = (_Float16)0.0f; bf[7] = (_Float16)0.0f;
        }
    }

    // Lane's A stream: tile t at abase + t*1024B, lane offset (l&31)*32 + (l>>5)*16.
    const f16x8* ap = (const f16x8*)abase + (size_t)n * 2 + g;
    const f32x16 cz = {0.0f, 0.0f, 0.0f, 0.0f, 0.0f, 0.0f, 0.0f, 0.0f,
                       0.0f, 0.0f, 0.0f, 0.0f, 0.0f, 0.0f, 0.0f, 0.0f};

    // Depth-4 prefetch ring to cover ~200 cyc L1/L2 latency.
    f16x8 ar[4];
    #pragma unroll
    for (int i = 0; i < 4; ++i) ar[i] = ap[(size_t)i * 64];

    float acc0 = 1e30f, acc1 = 1e30f;                 // 2 independent fold chains
    #pragma unroll 1
    for (int t = 0; t < 128; ++t) {
        f32x16 c = __builtin_amdgcn_mfma_f32_32x32x16_f16(ar[t & 3], bf, cz, 0, 0, 0);
        if (t < 124)
            ar[t & 3] = ap[(size_t)(t + 4) * 64];
        #pragma unroll
        for (int r = 0; r < 8; r += 2) {
            acc0 = fminf(acc0, fminf(c[r],     c[r + 1]));      // -> v_min3
            acc1 = fminf(acc1, fminf(c[r + 8], c[r + 9]));
        }
    }

    // Rows split across lane halves; fold, then epilogue.
    float v = fminf(acc0, acc1);
    v = fminf(v, __shfl_xor(v, 32));
    float d = fmaxf(v + p2, 0.0f);                     // == min of clamped (monotone)
    float s = sqrtf(d) * INV_CNT;
    if (g != 0) s = 0.0f;                              // count each query once
    #pragma unroll
    for (int off = 32; off > 0; off >>= 1) s += __shfl_down(s, off);
    if (lane == 0) wsum[wv] = s;
    __syncthreads();
    if (tid == 0) {
        float t = 0.0f;
        #pragma unroll
        for (int i = 0; i < BLOCK / 64; ++i) t += wsum[i];
        atomicAdd(out, t);                             // 256 atomics total
    }
}

extern "C" void kernel_launch(void* const* d_in, const int* in_sizes, int n_in,
                              void* d_out, int out_size, void* d_ws, size_t ws_size,
                              hipStream_t stream) {
    const float* tpl = (const float*)d_in[0];
    const float* src = (const float*)d_in[1];
    float* out = (float*)d_out;
    _Float16* arow = (_Float16*)d_ws;                  // 131072 pts x 32 B = 4 MB

    hipLaunchKernelGGL(prep_kernel, dim3((2 * N_BATCH * N_PTS) / 256),
                       dim3(256), 0, stream, tpl, src, arow, out);
    dim3 grid(N_PTS / 512, N_BATCH, 2);                // (8, 16, 2) = 256 blocks
    hipLaunchKernelGGL(chamfer_mfma, grid, dim3(BLOCK), 0, stream,
                       tpl, src, arow, out);
}

// Round 8
// 98.803 us; speedup vs baseline: 19.4557x; 19.4557x over previous
//
#include <hip/hip_runtime.h>

#define N_PTS   4096
#define N_BATCH 16
#define INV_CNT (1.0f / (2.0f * N_BATCH * N_PTS))
#define AROW_BYTES ((size_t)2 * N_BATCH * N_PTS * 16 * 2)   // 4 MB
#define NBLK    1024               // main-kernel blocks

typedef _Float16 f16x8  __attribute__((ext_vector_type(8)));
typedef float    f32x16 __attribute__((ext_vector_type(16)));

// 32x32x16 f16 MFMA, K-slot packing (split o = oh + ol, p = ph + pl in f16):
//   A-row (opposite point o): [-2oh_x,-2oh_y,-2oh_z, -2ol_x,-2ol_y,-2ol_z,
//                              -2oh_x,-2oh_y | -2oh_z, o2h, o2l, 0...]
//   B-col (query p):          [ph_x,ph_y,ph_z, ph_x,ph_y,ph_z, pl_x,pl_y |
//                              pl_z, 1, 1, 0...]
//   => C = |o|^2 - 2 o.p   (dropped ol.pl ~2^-22; verified R5-R7, absmax 0.0)
// A lane layout: row=l&31, k=(l>>5)*8+j -> one contiguous 16 B load per lane.
__global__ __launch_bounds__(256) void prep_kernel(
    const float* __restrict__ tpl, const float* __restrict__ src,
    _Float16* __restrict__ arow, float* __restrict__ out) {
    int pt = blockIdx.x * 256 + threadIdx.x;          // 0..131071 (T set, then S set)
    if (pt == 0) out[0] = 0.0f;                       // fallback path runs after
    const float* p = (pt < 65536 ? tpl : src) + (size_t)(pt & 65535) * 3;
    float x = p[0], y = p[1], z = p[2];
    float o2 = fmaf(x, x, fmaf(y, y, z * z));
    _Float16 xh = (_Float16)x, yh = (_Float16)y, zh = (_Float16)z;
    _Float16 xl = (_Float16)(x - (float)xh);
    _Float16 yl = (_Float16)(y - (float)yh);
    _Float16 zl = (_Float16)(z - (float)zh);
    _Float16 o2h = (_Float16)o2;
    _Float16 o2l = (_Float16)(o2 - (float)o2h);
    const _Float16 m2 = (_Float16)-2.0f;              // exact power-of-2 scale
    f16x8 v0, v1;
    v0[0] = m2 * xh; v0[1] = m2 * yh; v0[2] = m2 * zh;
    v0[3] = m2 * xl; v0[4] = m2 * yl; v0[5] = m2 * zl;
    v0[6] = m2 * xh; v0[7] = m2 * yh;
    v1[0] = m2 * zh; v1[1] = o2h; v1[2] = o2l;
    v1[3] = (_Float16)0.0f; v1[4] = (_Float16)0.0f; v1[5] = (_Float16)0.0f;
    v1[6] = (_Float16)0.0f; v1[7] = (_Float16)0.0f;
    *(f16x8*)(arow + (size_t)pt * 16)     = v0;
    *(f16x8*)(arow + (size_t)pt * 16 + 8) = v1;
}

#define FOLD(c)                                                   \
    _Pragma("unroll")                                             \
    for (int r = 0; r < 8; r += 2) {                              \
        acc0 = fminf(acc0, fminf((c)[r],     (c)[r + 1]));        \
        acc1 = fminf(acc1, fminf((c)[r + 8], (c)[r + 9]));        \
    }

// Grid (32, 16, 2) = 1024 blocks x 4 waves = 4 blocks/CU = 16 waves/CU.
// Wave owns 32 queries (1 B-frag); streams 128 A-tiles direct global->register
// with a STATIC depth-4 ring (named regs a0..a3 -- R7's ar[t&3] went to scratch).
__global__ __launch_bounds__(256, 4) void chamfer_mfma(
    const float* __restrict__ tpl, const float* __restrict__ src,
    const _Float16* __restrict__ arow, float* __restrict__ blocksum,
    float* __restrict__ out) {
    __shared__ float wsum[4];

    const int tid = threadIdx.x;
    const int wv = tid >> 6, lane = tid & 63;
    const int n = lane & 31, g = lane >> 5;           // B col / K-half group
    const int qb = blockIdx.x, batch = blockIdx.y, dir = blockIdx.z;

    const float* qpts = (dir == 0) ? src : tpl;       // dist1: query = source
    const _Float16* abase = arow + ((dir == 0) ? (size_t)0 : (size_t)65536 * 16)
                          + (size_t)batch * 4096 * 16;

    // B fragment + |p|^2 (lane n -> query qb*128 + wv*32 + n).
    const int q = qb * 128 + wv * 32 + n;
    const float* p = qpts + (size_t)(batch * 4096 + q) * 3;
    float px = p[0], py = p[1], pz = p[2];
    float p2 = fmaf(px, px, fmaf(py, py, pz * pz));
    f16x8 bf;
    {
        _Float16 xh = (_Float16)px, yh = (_Float16)py, zh = (_Float16)pz;
        _Float16 xl = (_Float16)(px - (float)xh);
        _Float16 yl = (_Float16)(py - (float)yh);
        _Float16 zl = (_Float16)(pz - (float)zh);
        if (g == 0) {
            bf[0] = xh; bf[1] = yh; bf[2] = zh;
            bf[3] = xh; bf[4] = yh; bf[5] = zh;
            bf[6] = xl; bf[7] = yl;
        } else {
            bf[0] = zl; bf[1] = (_Float16)1.0f; bf[2] = (_Float16)1.0f;
            bf[3] = (_Float16)0.0f; bf[4] = (_Float16)0.0f; bf[5] = (_Float16)0.0f;
            bf[6] = (_Float16)0.0f; bf[7] = (_Float16)0.0f;
        }
    }

    // Lane A stream: tile t at +t*1024 B; lane offset (l&31)*32 + (l>>5)*16 B.
    const f16x8* ap = (const f16x8*)abase + (size_t)n * 2 + g;
    const f32x16 cz = {0.0f, 0.0f, 0.0f, 0.0f, 0.0f, 0.0f, 0.0f, 0.0f,
                       0.0f, 0.0f, 0.0f, 0.0f, 0.0f, 0.0f, 0.0f, 0.0f};

    f16x8 a0 = ap[0 * 64], a1 = ap[1 * 64], a2 = ap[2 * 64], a3 = ap[3 * 64];
    float acc0 = 1e30f, acc1 = 1e30f;                 // 2 independent fold chains
    #pragma unroll 1
    for (int t = 0; t < 128; t += 4) {
        // Prefetch wraps (&127) back into the same region: harmless, branch-free.
        f32x16 c0 = __builtin_amdgcn_mfma_f32_32x32x16_f16(a0, bf, cz, 0, 0, 0);
        a0 = ap[(size_t)((t + 4) & 127) * 64];
        f32x16 c1 = __builtin_amdgcn_mfma_f32_32x32x16_f16(a1, bf, cz, 0, 0, 0);
        a1 = ap[(size_t)((t + 5) & 127) * 64];
        FOLD(c0)
        f32x16 c2 = __builtin_amdgcn_mfma_f32_32x32x16_f16(a2, bf, cz, 0, 0, 0);
        a2 = ap[(size_t)((t + 6) & 127) * 64];
        FOLD(c1)
        f32x16 c3 = __builtin_amdgcn_mfma_f32_32x32x16_f16(a3, bf, cz, 0, 0, 0);
        a3 = ap[(size_t)((t + 7) & 127) * 64];
        FOLD(c2)
        FOLD(c3)
    }

    // Rows split across lane halves; fold, then epilogue.
    float v = fminf(acc0, acc1);
    v = fminf(v, __shfl_xor(v, 32));
    float d = fmaxf(v + p2, 0.0f);                     // == min of clamped (monotone)
    float s = sqrtf(d) * INV_CNT;
    if (g != 0) s = 0.0f;                              // count each query once
    #pragma unroll
    for (int off = 32; off > 0; off >>= 1) s += __shfl_down(s, off);
    if (lane == 0) wsum[wv] = s;
    __syncthreads();
    if (tid == 0) {
        float t = wsum[0] + wsum[1] + wsum[2] + wsum[3];
        if (blocksum) {
            int flat = (blockIdx.z * N_BATCH + blockIdx.y) * 32 + blockIdx.x;
            blocksum[flat] = t;                        // unique slot: no atomics
        } else {
            atomicAdd(out, t);                         // fallback (small ws)
        }
    }
}

// Reduce 1024 block sums -> out[0]. Single block, no atomics.
__global__ __launch_bounds__(256) void final_kernel(
    const float* __restrict__ blocksum, float* __restrict__ out) {
    __shared__ float wsum[4];
    float s = 0.0f;
    #pragma unroll
    for (int j = 0; j < NBLK / 256; ++j)
        s += blocksum[j * 256 + threadIdx.x];
    #pragma unroll
    for (int off = 32; off > 0; off >>= 1) s += __shfl_down(s, off);
    if ((threadIdx.x & 63) == 0) wsum[threadIdx.x >> 6] = s;
    __syncthreads();
    if (threadIdx.x == 0) out[0] = wsum[0] + wsum[1] + wsum[2] + wsum[3];
}

extern "C" void kernel_launch(void* const* d_in, const int* in_sizes, int n_in,
                              void* d_out, int out_size, void* d_ws, size_t ws_size,
                              hipStream_t stream) {
    const float* tpl = (const float*)d_in[0];
    const float* src = (const float*)d_in[1];
    float* out = (float*)d_out;
    _Float16* arow = (_Float16*)d_ws;                  // 4 MB
    const bool roomy = ws_size >= AROW_BYTES + NBLK * sizeof(float);
    float* blocksum = roomy ? (float*)((char*)d_ws + AROW_BYTES) : nullptr;

    hipLaunchKernelGGL(prep_kernel, dim3((2 * N_BATCH * N_PTS) / 256),
                       dim3(256), 0, stream, tpl, src, arow, out);
    dim3 grid(N_PTS / 128, N_BATCH, 2);                // (32, 16, 2) = 1024 blocks
    hipLaunchKernelGGL(chamfer_mfma, grid, dim3(256), 0, stream,
                       tpl, src, arow, blocksum, out);
    if (roomy)
        hipLaunchKernelGGL(final_kernel, dim3(1), dim3(256), 0, stream,
                           blocksum, out);
}

// Round 9
// 95.518 us; speedup vs baseline: 20.1248x; 1.0344x over previous
//
#include <hip/hip_runtime.h>

#define N_PTS   4096
#define N_BATCH 16
#define INV_CNT (1.0f / (2.0f * N_BATCH * N_PTS))
#define AROW_BYTES ((size_t)2 * N_BATCH * N_PTS * 16 * 2)   // 4 MB
#define NBLK    1024               // main-kernel blocks

typedef _Float16 f16x8  __attribute__((ext_vector_type(8)));
typedef float    f32x16 __attribute__((ext_vector_type(16)));

// 32x32x16 f16 MFMA, K-slot packing (split o = oh + ol, p = ph + pl in f16):
//   A-row (opposite point o): [-2oh_x,-2oh_y,-2oh_z, -2ol_x,-2ol_y,-2ol_z,
//                              -2oh_x,-2oh_y | -2oh_z, o2h, o2l, 0...]
//   B-col (query p):          [ph_x,ph_y,ph_z, ph_x,ph_y,ph_z, pl_x,pl_y |
//                              pl_z, 1, 1, 0...]
//   => C = |o|^2 - 2 o.p   (dropped ol.pl ~2^-22; verified R5-R8, absmax 0.0)
// A lane layout: row=l&31, k=(l>>5)*8+j -> one contiguous 16 B load per lane.
__global__ __launch_bounds__(256) void prep_kernel(
    const float* __restrict__ tpl, const float* __restrict__ src,
    _Float16* __restrict__ arow, float* __restrict__ out) {
    int pt = blockIdx.x * 256 + threadIdx.x;          // 0..131071 (T set, then S set)
    if (pt == 0) out[0] = 0.0f;                       // fallback path runs after
    const float* p = (pt < 65536 ? tpl : src) + (size_t)(pt & 65535) * 3;
    float x = p[0], y = p[1], z = p[2];
    float o2 = fmaf(x, x, fmaf(y, y, z * z));
    _Float16 xh = (_Float16)x, yh = (_Float16)y, zh = (_Float16)z;
    _Float16 xl = (_Float16)(x - (float)xh);
    _Float16 yl = (_Float16)(y - (float)yh);
    _Float16 zl = (_Float16)(z - (float)zh);
    _Float16 o2h = (_Float16)o2;
    _Float16 o2l = (_Float16)(o2 - (float)o2h);
    const _Float16 m2 = (_Float16)-2.0f;              // exact power-of-2 scale
    f16x8 v0, v1;
    v0[0] = m2 * xh; v0[1] = m2 * yh; v0[2] = m2 * zh;
    v0[3] = m2 * xl; v0[4] = m2 * yl; v0[5] = m2 * zl;
    v0[6] = m2 * xh; v0[7] = m2 * yh;
    v1[0] = m2 * zh; v1[1] = o2h; v1[2] = o2l;
    v1[3] = (_Float16)0.0f; v1[4] = (_Float16)0.0f; v1[5] = (_Float16)0.0f;
    v1[6] = (_Float16)0.0f; v1[7] = (_Float16)0.0f;
    *(f16x8*)(arow + (size_t)pt * 16)     = v0;
    *(f16x8*)(arow + (size_t)pt * 16 + 8) = v1;
}

#define FOLD(c)                                                   \
    _Pragma("unroll")                                             \
    for (int r = 0; r < 8; r += 2) {                              \
        acc0 = fminf(acc0, fminf((c)[r],     (c)[r + 1]));        \
        acc1 = fminf(acc1, fminf((c)[r + 8], (c)[r + 9]));        \
    }

// Grid (32, 16, 2) = 1024 blocks x 4 waves = 4 blocks/CU = 16 waves/CU.
// Wave: 32 queries, 128 A-tiles direct global->register, static depth-4 ring.
// R9: loads use IMMEDIATE offsets (0/1024/2048/3072) off one wave-uniform
// pointer bumped once per 4-tile group -- kills R8's per-load address chains;
// MFMA/FOLD interleave keeps <=2 C tuples live (halve AGPR copy pressure).
__global__ __launch_bounds__(256, 4) void chamfer_mfma(
    const float* __restrict__ tpl, const float* __restrict__ src,
    const _Float16* __restrict__ arow, float* __restrict__ blocksum,
    float* __restrict__ out) {
    __shared__ float wsum[4];

    const int tid = threadIdx.x;
    const int wv = tid >> 6, lane = tid & 63;
    const int n = lane & 31, g = lane >> 5;           // B col / K-half group
    const int qb = blockIdx.x, batch = blockIdx.y, dir = blockIdx.z;

    const float* qpts = (dir == 0) ? src : tpl;       // dist1: query = source
    const _Float16* abase = arow + ((dir == 0) ? (size_t)0 : (size_t)65536 * 16)
                          + (size_t)batch * 4096 * 16;

    // B fragment + |p|^2 (lane n -> query qb*128 + wv*32 + n).
    const int q = qb * 128 + wv * 32 + n;
    const float* p = qpts + (size_t)(batch * 4096 + q) * 3;
    float px = p[0], py = p[1], pz = p[2];
    float p2 = fmaf(px, px, fmaf(py, py, pz * pz));
    f16x8 bf;
    {
        _Float16 xh = (_Float16)px, yh = (_Float16)py, zh = (_Float16)pz;
        _Float16 xl = (_Float16)(px - (float)xh);
        _Float16 yl = (_Float16)(py - (float)yh);
        _Float16 zl = (_Float16)(pz - (float)zh);
        if (g == 0) {
            bf[0] = xh; bf[1] = yh; bf[2] = zh;
            bf[3] = xh; bf[4] = yh; bf[5] = zh;
            bf[6] = xl; bf[7] = yl;
        } else {
            bf[0] = zl; bf[1] = (_Float16)1.0f; bf[2] = (_Float16)1.0f;
            bf[3] = (_Float16)0.0f; bf[4] = (_Float16)0.0f; bf[5] = (_Float16)0.0f;
            bf[6] = (_Float16)0.0f; bf[7] = (_Float16)0.0f;
        }
    }

    // Lane A stream: tile t at +t*1024 B; lane offset n*32 + g*16 B.
    const char* aptr = (const char*)abase + (n * 32 + g * 16);
    const f32x16 cz = {0.0f, 0.0f, 0.0f, 0.0f, 0.0f, 0.0f, 0.0f, 0.0f,
                       0.0f, 0.0f, 0.0f, 0.0f, 0.0f, 0.0f, 0.0f, 0.0f};

    f16x8 a0 = *(const f16x8*)(aptr +    0);
    f16x8 a1 = *(const f16x8*)(aptr + 1024);
    f16x8 a2 = *(const f16x8*)(aptr + 2048);
    f16x8 a3 = *(const f16x8*)(aptr + 3072);
    float acc0 = 1e30f, acc1 = 1e30f;                 // 2 independent fold chains

    #pragma unroll 1
    for (int it = 0; it < 31; ++it) {                 // tiles 0..123 (31 groups)
        aptr += 4096;                                 // one uniform bump / group
        f32x16 c0 = __builtin_amdgcn_mfma_f32_32x32x16_f16(a0, bf, cz, 0, 0, 0);
        a0 = *(const f16x8*)(aptr +    0);            // imm-offset prefetches
        f32x16 c1 = __builtin_amdgcn_mfma_f32_32x32x16_f16(a1, bf, cz, 0, 0, 0);
        a1 = *(const f16x8*)(aptr + 1024);
        FOLD(c0)
        f32x16 c2 = __builtin_amdgcn_mfma_f32_32x32x16_f16(a2, bf, cz, 0, 0, 0);
        a2 = *(const f16x8*)(aptr + 2048);
        FOLD(c1)
        f32x16 c3 = __builtin_amdgcn_mfma_f32_32x32x16_f16(a3, bf, cz, 0, 0, 0);
        a3 = *(const f16x8*)(aptr + 3072);
        FOLD(c2)
        FOLD(c3)
    }
    {                                                 // peeled group: tiles 124..127
        f32x16 c0 = __builtin_amdgcn_mfma_f32_32x32x16_f16(a0, bf, cz, 0, 0, 0);
        f32x16 c1 = __builtin_amdgcn_mfma_f32_32x32x16_f16(a1, bf, cz, 0, 0, 0);
        FOLD(c0)
        f32x16 c2 = __builtin_amdgcn_mfma_f32_32x32x16_f16(a2, bf, cz, 0, 0, 0);
        FOLD(c1)
        f32x16 c3 = __builtin_amdgcn_mfma_f32_32x32x16_f16(a3, bf, cz, 0, 0, 0);
        FOLD(c2)
        FOLD(c3)
    }

    // Rows split across lane halves; fold, then epilogue.
    float v = fminf(acc0, acc1);
    v = fminf(v, __shfl_xor(v, 32));
    float d = fmaxf(v + p2, 0.0f);                     // == min of clamped (monotone)
    float s = sqrtf(d) * INV_CNT;
    if (g != 0) s = 0.0f;                              // count each query once
    #pragma unroll
    for (int off = 32; off > 0; off >>= 1) s += __shfl_down(s, off);
    if (lane == 0) wsum[wv] = s;
    __syncthreads();
    if (tid == 0) {
        float t = wsum[0] + wsum[1] + wsum[2] + wsum[3];
        if (blocksum) {
            int flat = (blockIdx.z * N_BATCH + blockIdx.y) * 32 + blockIdx.x;
            blocksum[flat] = t;                        // unique slot: no atomics
        } else {
            atomicAdd(out, t);                         // fallback (small ws)
        }
    }
}

// Reduce 1024 block sums -> out[0]. Single block, no atomics.
__global__ __launch_bounds__(256) void final_kernel(
    const float* __restrict__ blocksum, float* __restrict__ out) {
    __shared__ float wsum[4];
    float s = 0.0f;
    #pragma unroll
    for (int j = 0; j < NBLK / 256; ++j)
        s += blocksum[j * 256 + threadIdx.x];
    #pragma unroll
    for (int off = 32; off > 0; off >>= 1) s += __shfl_down(s, off);
    if ((threadIdx.x & 63) == 0) wsum[threadIdx.x >> 6] = s;
    __syncthreads();
    if (threadIdx.x == 0) out[0] = wsum[0] + wsum[1] + wsum[2] + wsum[3];
}

extern "C" void kernel_launch(void* const* d_in, const int* in_sizes, int n_in,
                              void* d_out, int out_size, void* d_ws, size_t ws_size,
                              hipStream_t stream) {
    const float* tpl = (const float*)d_in[0];
    const float* src = (const float*)d_in[1];
    float* out = (float*)d_out;
    _Float16* arow = (_Float16*)d_ws;                  // 4 MB
    const bool roomy = ws_size >= AROW_BYTES + NBLK * sizeof(float);
    float* blocksum = roomy ? (float*)((char*)d_ws + AROW_BYTES) : nullptr;

    hipLaunchKernelGGL(prep_kernel, dim3((2 * N_BATCH * N_PTS) / 256),
                       dim3(256), 0, stream, tpl, src, arow, out);
    dim3 grid(N_PTS / 128, N_BATCH, 2);                // (32, 16, 2) = 1024 blocks
    hipLaunchKernelGGL(chamfer_mfma, grid, dim3(256), 0, stream,
                       tpl, src, arow, blocksum, out);
    if (roomy)
        hipLaunchKernelGGL(final_kernel, dim3(1), dim3(256), 0, stream,
                           blocksum, out);
}

// Round 10
// 95.140 us; speedup vs baseline: 20.2049x; 1.0040x over previous
//
#include <hip/hip_runtime.h>

#define N_PTS   4096
#define N_BATCH 16
#define INV_CNT (1.0f / (2.0f * N_BATCH * N_PTS))
#define AROW_BYTES ((size_t)2 * N_BATCH * N_PTS * 16 * 2)   // 4 MB
#define NBLK    1024               // main-kernel blocks

typedef _Float16 f16x8  __attribute__((ext_vector_type(8)));
typedef float    f32x16 __attribute__((ext_vector_type(16)));

// 32x32x16 f16 MFMA, K-slot packing (split o = oh + ol, p = ph + pl in f16):
//   A-row (opposite point o): [-2oh_x,-2oh_y,-2oh_z, -2ol_x,-2ol_y,-2ol_z,
//                              -2oh_x,-2oh_y | -2oh_z, o2h, o2l, 0...]
//   B-col (query p):          [ph_x,ph_y,ph_z, ph_x,ph_y,ph_z, pl_x,pl_y |
//                              pl_z, 1, 1, 0...]
//   => C = |o|^2 - 2 o.p   (dropped ol.pl ~2^-22; verified R5-R9, absmax 0.0)
// A lane layout: row=l&31, k=(l>>5)*8+j -> one contiguous 16 B load per lane.
__global__ __launch_bounds__(256) void prep_kernel(
    const float* __restrict__ tpl, const float* __restrict__ src,
    _Float16* __restrict__ arow, float* __restrict__ out) {
    int pt = blockIdx.x * 256 + threadIdx.x;          // 0..131071 (T set, then S set)
    if (pt == 0) out[0] = 0.0f;                       // fallback path runs after
    const float* p = (pt < 65536 ? tpl : src) + (size_t)(pt & 65535) * 3;
    float x = p[0], y = p[1], z = p[2];
    float o2 = fmaf(x, x, fmaf(y, y, z * z));
    _Float16 xh = (_Float16)x, yh = (_Float16)y, zh = (_Float16)z;
    _Float16 xl = (_Float16)(x - (float)xh);
    _Float16 yl = (_Float16)(y - (float)yh);
    _Float16 zl = (_Float16)(z - (float)zh);
    _Float16 o2h = (_Float16)o2;
    _Float16 o2l = (_Float16)(o2 - (float)o2h);
    const _Float16 m2 = (_Float16)-2.0f;              // exact power-of-2 scale
    f16x8 v0, v1;
    v0[0] = m2 * xh; v0[1] = m2 * yh; v0[2] = m2 * zh;
    v0[3] = m2 * xl; v0[4] = m2 * yl; v0[5] = m2 * zl;
    v0[6] = m2 * xh; v0[7] = m2 * yh;
    v1[0] = m2 * zh; v1[1] = o2h; v1[2] = o2l;
    v1[3] = (_Float16)0.0f; v1[4] = (_Float16)0.0f; v1[5] = (_Float16)0.0f;
    v1[6] = (_Float16)0.0f; v1[7] = (_Float16)0.0f;
    *(f16x8*)(arow + (size_t)pt * 16)     = v0;
    *(f16x8*)(arow + (size_t)pt * 16 + 8) = v1;
}

#define FOLD(c)                                                   \
    _Pragma("unroll")                                             \
    for (int r = 0; r < 8; r += 2) {                              \
        acc0 = fminf(acc0, fminf((c)[r],     (c)[r + 1]));        \
        acc1 = fminf(acc1, fminf((c)[r + 8], (c)[r + 9]));        \
    }

// Grid (32, 16, 2) = 1024 blocks x 4 waves = 4 blocks/CU = 16 waves/CU.
// Wave: 32 queries, 128 A-tiles direct global->register, depth-4 A-ring.
// R10: ONE C tuple live at a time (MFMA -> prefetch -> FOLD immediately).
// R8/R9's manual 4-C interleave forced 64 C-regs live -> AGPR re-zero +
// accvgpr copies (~2.5x VALU bloat). Cross-wave scheduling (4 waves/SIMD)
// hides the MFMA-dest wait instead; compiler can keep C/D in VGPRs.
__global__ __launch_bounds__(256, 4) void chamfer_mfma(
    const float* __restrict__ tpl, const float* __restrict__ src,
    const _Float16* __restrict__ arow, float* __restrict__ blocksum,
    float* __restrict__ out) {
    __shared__ float wsum[4];

    const int tid = threadIdx.x;
    const int wv = tid >> 6, lane = tid & 63;
    const int n = lane & 31, g = lane >> 5;           // B col / K-half group
    const int qb = blockIdx.x, batch = blockIdx.y, dir = blockIdx.z;

    const float* qpts = (dir == 0) ? src : tpl;       // dist1: query = source
    const _Float16* abase = arow + ((dir == 0) ? (size_t)0 : (size_t)65536 * 16)
                          + (size_t)batch * 4096 * 16;

    // B fragment + |p|^2 (lane n -> query qb*128 + wv*32 + n).
    const int q = qb * 128 + wv * 32 + n;
    const float* p = qpts + (size_t)(batch * 4096 + q) * 3;
    float px = p[0], py = p[1], pz = p[2];
    float p2 = fmaf(px, px, fmaf(py, py, pz * pz));
    f16x8 bf;
    {
        _Float16 xh = (_Float16)px, yh = (_Float16)py, zh = (_Float16)pz;
        _Float16 xl = (_Float16)(px - (float)xh);
        _Float16 yl = (_Float16)(py - (float)yh);
        _Float16 zl = (_Float16)(pz - (float)zh);
        if (g == 0) {
            bf[0] = xh; bf[1] = yh; bf[2] = zh;
            bf[3] = xh; bf[4] = yh; bf[5] = zh;
            bf[6] = xl; bf[7] = yl;
        } else {
            bf[0] = zl; bf[1] = (_Float16)1.0f; bf[2] = (_Float16)1.0f;
            bf[3] = (_Float16)0.0f; bf[4] = (_Float16)0.0f; bf[5] = (_Float16)0.0f;
            bf[6] = (_Float16)0.0f; bf[7] = (_Float16)0.0f;
        }
    }

    // Lane A stream: tile t at +t*1024 B; lane offset n*32 + g*16 B.
    const char* aptr = (const char*)abase + (n * 32 + g * 16);
    const f32x16 cz = {0.0f, 0.0f, 0.0f, 0.0f, 0.0f, 0.0f, 0.0f, 0.0f,
                       0.0f, 0.0f, 0.0f, 0.0f, 0.0f, 0.0f, 0.0f, 0.0f};

    f16x8 a0 = *(const f16x8*)(aptr +    0);
    f16x8 a1 = *(const f16x8*)(aptr + 1024);
    f16x8 a2 = *(const f16x8*)(aptr + 2048);
    f16x8 a3 = *(const f16x8*)(aptr + 3072);
    float acc0 = 1e30f, acc1 = 1e30f;                 // 2 independent fold chains

    #pragma unroll 1
    for (int it = 0; it < 31; ++it) {                 // tiles 0..123 (31 groups)
        aptr += 4096;                                 // one uniform bump / group
        {
            f32x16 c = __builtin_amdgcn_mfma_f32_32x32x16_f16(a0, bf, cz, 0, 0, 0);
            a0 = *(const f16x8*)(aptr +    0);        // load issued before fold
            FOLD(c)                                   // c dies here: 1 C tuple live
        }
        {
            f32x16 c = __builtin_amdgcn_mfma_f32_32x32x16_f16(a1, bf, cz, 0, 0, 0);
            a1 = *(const f16x8*)(aptr + 1024);
            FOLD(c)
        }
        {
            f32x16 c = __builtin_amdgcn_mfma_f32_32x32x16_f16(a2, bf, cz, 0, 0, 0);
            a2 = *(const f16x8*)(aptr + 2048);
            FOLD(c)
        }
        {
            f32x16 c = __builtin_amdgcn_mfma_f32_32x32x16_f16(a3, bf, cz, 0, 0, 0);
            a3 = *(const f16x8*)(aptr + 3072);
            FOLD(c)
        }
    }
    {                                                 // peeled group: tiles 124..127
        f32x16 c0 = __builtin_amdgcn_mfma_f32_32x32x16_f16(a0, bf, cz, 0, 0, 0);
        FOLD(c0)
        f32x16 c1 = __builtin_amdgcn_mfma_f32_32x32x16_f16(a1, bf, cz, 0, 0, 0);
        FOLD(c1)
        f32x16 c2 = __builtin_amdgcn_mfma_f32_32x32x16_f16(a2, bf, cz, 0, 0, 0);
        FOLD(c2)
        f32x16 c3 = __builtin_amdgcn_mfma_f32_32x32x16_f16(a3, bf, cz, 0, 0, 0);
        FOLD(c3)
    }

    // Rows split across lane halves; fold, then epilogue.
    float v = fminf(acc0, acc1);
    v = fminf(v, __shfl_xor(v, 32));
    float d = fmaxf(v + p2, 0.0f);                     // == min of clamped (monotone)
    float s = sqrtf(d) * INV_CNT;
    if (g != 0) s = 0.0f;                              // count each query once
    #pragma unroll
    for (int off = 32; off > 0; off >>= 1) s += __shfl_down(s, off);
    if (lane == 0) wsum[wv] = s;
    __syncthreads();
    if (tid == 0) {
        float t = wsum[0] + wsum[1] + wsum[2] + wsum[3];
        if (blocksum) {
            int flat = (blockIdx.z * N_BATCH + blockIdx.y) * 32 + blockIdx.x;
            blocksum[flat] = t;                        // unique slot: no atomics
        } else {
            atomicAdd(out, t);                         // fallback (small ws)
        }
    }
}

// Reduce 1024 block sums -> out[0]. Single block, no atomics.
__global__ __launch_bounds__(256) void final_kernel(
    const float* __restrict__ blocksum, float* __restrict__ out) {
    __shared__ float wsum[4];
    float s = 0.0f;
    #pragma unroll
    for (int j = 0; j < NBLK / 256; ++j)
        s += blocksum[j * 256 + threadIdx.x];
    #pragma unroll
    for (int off = 32; off > 0; off >>= 1) s += __shfl_down(s, off);
    if ((threadIdx.x & 63) == 0) wsum[threadIdx.x >> 6] = s;
    __syncthreads();
    if (threadIdx.x == 0) out[0] = wsum[0] + wsum[1] + wsum[2] + wsum[3];
}

extern "C" void kernel_launch(void* const* d_in, const int* in_sizes, int n_in,
                              void* d_out, int out_size, void* d_ws, size_t ws_size,
                              hipStream_t stream) {
    const float* tpl = (const float*)d_in[0];
    const float* src = (const float*)d_in[1];
    float* out = (float*)d_out;
    _Float16* arow = (_Float16*)d_ws;                  // 4 MB
    const bool roomy = ws_size >= AROW_BYTES + NBLK * sizeof(float);
    float* blocksum = roomy ? (float*)((char*)d_ws + AROW_BYTES) : nullptr;

    hipLaunchKernelGGL(prep_kernel, dim3((2 * N_BATCH * N_PTS) / 256),
                       dim3(256), 0, stream, tpl, src, arow, out);
    dim3 grid(N_PTS / 128, N_BATCH, 2);                // (32, 16, 2) = 1024 blocks
    hipLaunchKernelGGL(chamfer_mfma, grid, dim3(256), 0, stream,
                       tpl, src, arow, blocksum, out);
    if (roomy)
        hipLaunchKernelGGL(final_kernel, dim3(1), dim3(256), 0, stream,
                           blocksum, out);
}

// Round 11
// 81.220 us; speedup vs baseline: 23.6676x; 1.1714x over previous
//
#include <hip/hip_runtime.h>

#define N_PTS   4096
#define N_BATCH 16
#define INV_CNT (1.0f / (2.0f * N_BATCH * N_PTS))
#define AROW_BYTES ((size_t)2 * N_BATCH * N_PTS * 16 * 2)   // 4 MB
#define NBLK    1024               // main-kernel blocks

typedef _Float16 f16x8  __attribute__((ext_vector_type(8)));

// 32x32x16 f16 MFMA, K-slot packing (split o = oh + ol, p = ph + pl in f16):
//   A-row (opposite point o): [-2oh_x,-2oh_y,-2oh_z, -2ol_x,-2ol_y,-2ol_z,
//                              -2oh_x,-2oh_y | -2oh_z, o2h, o2l, 0...]
//   B-col (query p):          [ph_x,ph_y,ph_z, ph_x,ph_y,ph_z, pl_x,pl_y |
//                              pl_z, 1, 1, 0...]
//   => C = |o|^2 - 2 o.p   (dropped ol.pl ~2^-22; verified R5-R10, absmax 0.0)
// A lane layout: row=l&31, k=(l>>5)*8+j -> one contiguous 16 B load per lane.
__global__ __launch_bounds__(256) void prep_kernel(
    const float* __restrict__ tpl, const float* __restrict__ src,
    _Float16* __restrict__ arow, float* __restrict__ out) {
    int pt = blockIdx.x * 256 + threadIdx.x;          // 0..131071 (T set, then S set)
    if (pt == 0) out[0] = 0.0f;                       // fallback path runs after
    const float* p = (pt < 65536 ? tpl : src) + (size_t)(pt & 65535) * 3;
    float x = p[0], y = p[1], z = p[2];
    float o2 = fmaf(x, x, fmaf(y, y, z * z));
    _Float16 xh = (_Float16)x, yh = (_Float16)y, zh = (_Float16)z;
    _Float16 xl = (_Float16)(x - (float)xh);
    _Float16 yl = (_Float16)(y - (float)yh);
    _Float16 zl = (_Float16)(z - (float)zh);
    _Float16 o2h = (_Float16)o2;
    _Float16 o2l = (_Float16)(o2 - (float)o2h);
    const _Float16 m2 = (_Float16)-2.0f;              // exact power-of-2 scale
    f16x8 v0, v1;
    v0[0] = m2 * xh; v0[1] = m2 * yh; v0[2] = m2 * zh;
    v0[3] = m2 * xl; v0[4] = m2 * yl; v0[5] = m2 * zl;
    v0[6] = m2 * xh; v0[7] = m2 * yh;
    v1[0] = m2 * zh; v1[1] = o2h; v1[2] = o2l;
    v1[3] = (_Float16)0.0f; v1[4] = (_Float16)0.0f; v1[5] = (_Float16)0.0f;
    v1[6] = (_Float16)0.0f; v1[7] = (_Float16)0.0f;
    *(f16x8*)(arow + (size_t)pt * 16)     = v0;
    *(f16x8*)(arow + (size_t)pt * 16 + 8) = v1;
}

// ---- inline-asm building blocks (D0=v[32:47] D1=v[48:63] D2=v[64:79]
//      D3=v[80:95], zero-C pinned in v[96:111], zeroed ONCE) ----
#define FD(a,x,y) "v_min3_f32 %[" #a "], v" #x ", v" #y ", %[" #a "]\n\t"
#define FOLD_D0 FD(acc0,32,33) FD(acc1,34,35) FD(acc0,36,37) FD(acc1,38,39) \
                FD(acc0,40,41) FD(acc1,42,43) FD(acc0,44,45) FD(acc1,46,47)
#define FOLD_D1 FD(acc0,48,49) FD(acc1,50,51) FD(acc0,52,53) FD(acc1,54,55) \
                FD(acc0,56,57) FD(acc1,58,59) FD(acc0,60,61) FD(acc1,62,63)
#define FOLD_D2 FD(acc0,64,65) FD(acc1,66,67) FD(acc0,68,69) FD(acc1,70,71) \
                FD(acc0,72,73) FD(acc1,74,75) FD(acc0,76,77) FD(acc1,78,79)
#define FOLD_D3 FD(acc0,80,81) FD(acc1,82,83) FD(acc0,84,85) FD(acc1,86,87) \
                FD(acc0,88,89) FD(acc1,90,91) FD(acc0,92,93) FD(acc1,94,95)
#define MF0(a) "v_mfma_f32_32x32x16_f16 v[32:47], %[" #a "], %[bf], v[96:111]\n\t"
#define MF1(a) "v_mfma_f32_32x32x16_f16 v[48:63], %[" #a "], %[bf], v[96:111]\n\t"
#define MF2(a) "v_mfma_f32_32x32x16_f16 v[64:79], %[" #a "], %[bf], v[96:111]\n\t"
#define MF3(a) "v_mfma_f32_32x32x16_f16 v[80:95], %[" #a "], %[bf], v[96:111]\n\t"
#define LD(a,off) "global_load_dwordx4 %[" #a "], %[voff], %[sb] offset:" #off "\n\t"
#define WNOP(n) "s_waitcnt vmcnt(" #n ")\n\t" "s_nop 1\n\t"
#define ZM(r) "v_mov_b32 v" #r ", 0\n\t"

// Grid (32, 16, 2) = 1024 blocks x 4 waves = 16 waves/CU (4/SIMD).
// R11: hand-written K-loop. R8-R10 counters proved the intrinsic codegen
// emits ~60 VALU/tile (AGPR zero+copy traffic); this loop is 8 v_min3 +
// 1 load + ~2 overhead per tile, D read directly by v_min3, C-zeros pinned.
__global__ __launch_bounds__(256, 4) void chamfer_mfma(
    const float* __restrict__ tpl, const float* __restrict__ src,
    const _Float16* __restrict__ arow, float* __restrict__ blocksum,
    float* __restrict__ out) {
    __shared__ float wsum[4];

    const int tid = threadIdx.x;
    const int wv = tid >> 6, lane = tid & 63;
    const int n = lane & 31, g = lane >> 5;           // B col / K-half group
    const int qb = blockIdx.x, batch = blockIdx.y, dir = blockIdx.z;

    const float* qpts = (dir == 0) ? src : tpl;       // dist1: query = source
    const _Float16* abase = arow + ((dir == 0) ? (size_t)0 : (size_t)65536 * 16)
                          + (size_t)batch * 4096 * 16;

    // B fragment + |p|^2 (lane n -> query qb*128 + wv*32 + n).
    const int q = qb * 128 + wv * 32 + n;
    const float* p = qpts + (size_t)(batch * 4096 + q) * 3;
    float px = p[0], py = p[1], pz = p[2];
    float p2 = fmaf(px, px, fmaf(py, py, pz * pz));
    f16x8 bf;
    {
        _Float16 xh = (_Float16)px, yh = (_Float16)py, zh = (_Float16)pz;
        _Float16 xl = (_Float16)(px - (float)xh);
        _Float16 yl = (_Float16)(py - (float)yh);
        _Float16 zl = (_Float16)(pz - (float)zh);
        if (g == 0) {
            bf[0] = xh; bf[1] = yh; bf[2] = zh;
            bf[3] = xh; bf[4] = yh; bf[5] = zh;
            bf[6] = xl; bf[7] = yl;
        } else {
            bf[0] = zl; bf[1] = (_Float16)1.0f; bf[2] = (_Float16)1.0f;
            bf[3] = (_Float16)0.0f; bf[4] = (_Float16)0.0f; bf[5] = (_Float16)0.0f;
            bf[6] = (_Float16)0.0f; bf[7] = (_Float16)0.0f;
        }
    }

    int voff = n * 32 + g * 16;    // per-lane byte offset into A region
    int cnt = 30;                  // steady-state groups (1..30)
    float acc0 = 1e30f, acc1 = 1e30f;
    f16x8 ra0, ra1, ra2, ra3;      // A-ring, allocator-assigned tuples

    asm volatile(
        "s_waitcnt vmcnt(0)\n\t"
        // zero-C pinned v[96:111], once
        ZM(96) ZM(97) ZM(98) ZM(99) ZM(100) ZM(101) ZM(102) ZM(103)
        ZM(104) ZM(105) ZM(106) ZM(107) ZM(108) ZM(109) ZM(110) ZM(111)
        // prime ring: group 0
        LD(a0,0) LD(a1,1024) LD(a2,2048) LD(a3,3072)
        // prologue = group 0 (tiles 0-3): mfma only, reload for group 1
        "v_add_u32 %[voff], 0x1000, %[voff]\n\t"
        "s_waitcnt vmcnt(3)\n\t" MF0(a0) LD(a0,0)
        "s_waitcnt vmcnt(3)\n\t" MF1(a1) LD(a1,1024)
        "s_waitcnt vmcnt(3)\n\t" MF2(a2) LD(a2,2048)
        "s_waitcnt vmcnt(3)\n\t" MF3(a3) LD(a3,3072)
        // steady loop: groups 1..30 — fold prev group's D, mfma current
        "L_cham_%=:\n\t"
        "v_add_u32 %[voff], 0x1000, %[voff]\n\t"
        FOLD_D0 WNOP(3) MF0(a0) LD(a0,0)
        FOLD_D1 WNOP(3) MF1(a1) LD(a1,1024)
        FOLD_D2 WNOP(3) MF2(a2) LD(a2,2048)
        FOLD_D3 WNOP(3) MF3(a3) LD(a3,3072)
        "s_sub_u32 %[cnt], %[cnt], 1\n\t"
        "s_cmp_lg_u32 %[cnt], 0\n\t"
        "s_cbranch_scc1 L_cham_%=\n\t"
        // epilogue = group 31 (tiles 124-127): fold group 30, mfma, no loads
        FOLD_D0 WNOP(3) MF0(a0)
        FOLD_D1 WNOP(2) MF1(a1)
        FOLD_D2 WNOP(1) MF2(a2)
        FOLD_D3 WNOP(0) MF3(a3)
        // final folds of group 31 (D0 written 3 slots ago: RAW-safe)
        FOLD_D0 FOLD_D1 FOLD_D2 FOLD_D3
        : [a0]"=&v"(ra0), [a1]"=&v"(ra1), [a2]"=&v"(ra2), [a3]"=&v"(ra3),
          [voff]"+v"(voff), [cnt]"+s"(cnt), [acc0]"+v"(acc0), [acc1]"+v"(acc1)
        : [bf]"v"(bf), [sb]"s"(abase)
        : "memory", "scc",
          "v32","v33","v34","v35","v36","v37","v38","v39",
          "v40","v41","v42","v43","v44","v45","v46","v47",
          "v48","v49","v50","v51","v52","v53","v54","v55",
          "v56","v57","v58","v59","v60","v61","v62","v63",
          "v64","v65","v66","v67","v68","v69","v70","v71",
          "v72","v73","v74","v75","v76","v77","v78","v79",
          "v80","v81","v82","v83","v84","v85","v86","v87",
          "v88","v89","v90","v91","v92","v93","v94","v95",
          "v96","v97","v98","v99","v100","v101","v102","v103",
          "v104","v105","v106","v107","v108","v109","v110","v111");

    // Rows split across lane halves; fold, then epilogue.
    float v = fminf(acc0, acc1);
    v = fminf(v, __shfl_xor(v, 32));
    float d = fmaxf(v + p2, 0.0f);                     // == min of clamped (monotone)
    float s = sqrtf(d) * INV_CNT;
    if (g != 0) s = 0.0f;                              // count each query once
    #pragma unroll
    for (int off = 32; off > 0; off >>= 1) s += __shfl_down(s, off);
    if (lane == 0) wsum[wv] = s;
    __syncthreads();
    if (tid == 0) {
        float t = wsum[0] + wsum[1] + wsum[2] + wsum[3];
        if (blocksum) {
            int flat = (blockIdx.z * N_BATCH + blockIdx.y) * 32 + blockIdx.x;
            blocksum[flat] = t;                        // unique slot: no atomics
        } else {
            atomicAdd(out, t);                         // fallback (small ws)
        }
    }
}

// Reduce 1024 block sums -> out[0]. Single block, no atomics.
__global__ __launch_bounds__(256) void final_kernel(
    const float* __restrict__ blocksum, float* __restrict__ out) {
    __shared__ float wsum[4];
    float s = 0.0f;
    #pragma unroll
    for (int j = 0; j < NBLK / 256; ++j)
        s += blocksum[j * 256 + threadIdx.x];
    #pragma unroll
    for (int off = 32; off > 0; off >>= 1) s += __shfl_down(s, off);
    if ((threadIdx.x & 63) == 0) wsum[threadIdx.x >> 6] = s;
    __syncthreads();
    if (threadIdx.x == 0) out[0] = wsum[0] + wsum[1] + wsum[2] + wsum[3];
}

extern "C" void kernel_launch(void* const* d_in, const int* in_sizes, int n_in,
                              void* d_out, int out_size, void* d_ws, size_t ws_size,
                              hipStream_t stream) {
    const float* tpl = (const float*)d_in[0];
    const float* src = (const float*)d_in[1];
    float* out = (float*)d_out;
    _Float16* arow = (_Float16*)d_ws;                  // 4 MB
    const bool roomy = ws_size >= AROW_BYTES + NBLK * sizeof(float);
    float* blocksum = roomy ? (float*)((char*)d_ws + AROW_BYTES) : nullptr;

    hipLaunchKernelGGL(prep_kernel, dim3((2 * N_BATCH * N_PTS) / 256),
                       dim3(256), 0, stream, tpl, src, arow, out);
    dim3 grid(N_PTS / 128, N_BATCH, 2);                // (32, 16, 2) = 1024 blocks
    hipLaunchKernelGGL(chamfer_mfma, grid, dim3(256), 0, stream,
                       tpl, src, arow, blocksum, out);
    if (roomy)
        hipLaunchKernelGGL(final_kernel, dim3(1), dim3(256), 0, stream,
                           blocksum, out);
}

// Round 12
// 76.803 us; speedup vs baseline: 25.0289x; 1.0575x over previous
//
#include <hip/hip_runtime.h>

#define N_PTS   4096
#define N_BATCH 16
#define INV_CNT (1.0f / (2.0f * N_BATCH * N_PTS))
#define AROW_BYTES ((size_t)2 * N_BATCH * N_PTS * 16 * 2)   // 4 MB
#define NBLK    512                // main-kernel blocks

typedef _Float16 f16x8  __attribute__((ext_vector_type(8)));

// 32x32x16 f16 MFMA, K-slot packing (split o = oh + ol, p = ph + pl in f16):
//   A-row (opposite point o): [-2oh_x,-2oh_y,-2oh_z, -2ol_x,-2ol_y,-2ol_z,
//                              -2oh_x,-2oh_y | -2oh_z, o2h, o2l, 0...]
//   B-col (query p):          [ph_x,ph_y,ph_z, ph_x,ph_y,ph_z, pl_x,pl_y |
//                              pl_z, 1, 1, 0...]
//   => C = |o|^2 - 2 o.p   (dropped ol.pl ~2^-22; verified R5-R11, absmax 0.0)
// A lane layout: row=l&31, k=(l>>5)*8+j -> one contiguous 16 B load per lane.
__global__ __launch_bounds__(256) void prep_kernel(
    const float* __restrict__ tpl, const float* __restrict__ src,
    _Float16* __restrict__ arow, float* __restrict__ out) {
    int pt = blockIdx.x * 256 + threadIdx.x;          // 0..131071 (T set, then S set)
    if (pt == 0) out[0] = 0.0f;                       // fallback path runs after
    const float* p = (pt < 65536 ? tpl : src) + (size_t)(pt & 65535) * 3;
    float x = p[0], y = p[1], z = p[2];
    float o2 = fmaf(x, x, fmaf(y, y, z * z));
    _Float16 xh = (_Float16)x, yh = (_Float16)y, zh = (_Float16)z;
    _Float16 xl = (_Float16)(x - (float)xh);
    _Float16 yl = (_Float16)(y - (float)yh);
    _Float16 zl = (_Float16)(z - (float)zh);
    _Float16 o2h = (_Float16)o2;
    _Float16 o2l = (_Float16)(o2 - (float)o2h);
    const _Float16 m2 = (_Float16)-2.0f;              // exact power-of-2 scale
    f16x8 v0, v1;
    v0[0] = m2 * xh; v0[1] = m2 * yh; v0[2] = m2 * zh;
    v0[3] = m2 * xl; v0[4] = m2 * yl; v0[5] = m2 * zl;
    v0[6] = m2 * xh; v0[7] = m2 * yh;
    v1[0] = m2 * zh; v1[1] = o2h; v1[2] = o2l;
    v1[3] = (_Float16)0.0f; v1[4] = (_Float16)0.0f; v1[5] = (_Float16)0.0f;
    v1[6] = (_Float16)0.0f; v1[7] = (_Float16)0.0f;
    *(f16x8*)(arow + (size_t)pt * 16)     = v0;
    *(f16x8*)(arow + (size_t)pt * 16 + 8) = v1;
}

// ---- asm blocks. Pinned: D0a=v[32:47] D0b=v[48:63] (frag0 even/odd banks),
//      D1a=v[64:79] D1b=v[80:95] (frag1), zero-C=v[96:111] (zeroed once). ----
#define FD(a,x,y) "v_min3_f32 %[" #a "], v" #x ", v" #y ", %[" #a "]\n\t"
#define FOLD_D0A FD(acc0,32,33) FD(acc1,34,35) FD(acc0,36,37) FD(acc1,38,39) \
                 FD(acc0,40,41) FD(acc1,42,43) FD(acc0,44,45) FD(acc1,46,47)
#define FOLD_D0B FD(acc0,48,49) FD(acc1,50,51) FD(acc0,52,53) FD(acc1,54,55) \
                 FD(acc0,56,57) FD(acc1,58,59) FD(acc0,60,61) FD(acc1,62,63)
#define FOLD_D1A FD(acc2,64,65) FD(acc3,66,67) FD(acc2,68,69) FD(acc3,70,71) \
                 FD(acc2,72,73) FD(acc3,74,75) FD(acc2,76,77) FD(acc3,78,79)
#define FOLD_D1B FD(acc2,80,81) FD(acc3,82,83) FD(acc2,84,85) FD(acc3,86,87) \
                 FD(acc2,88,89) FD(acc3,90,91) FD(acc2,92,93) FD(acc3,94,95)
#define LD(s,off) "global_load_dwordx4 %[" #s "], %[voff], %[sb] offset:" #off "\n\t"
// even tile: write banks a, fold banks b (written 1 tile ago, ~42 cyc: RAW-safe)
#define TILE_E(s,off) "s_waitcnt vmcnt(7)\n\t" \
  "v_mfma_f32_32x32x16_f16 v[32:47], %[" #s "], %[bf0], v[96:111]\n\t" \
  "v_mfma_f32_32x32x16_f16 v[64:79], %[" #s "], %[bf1], v[96:111]\n\t" \
  LD(s,off) FOLD_D0B FOLD_D1B
// odd tile: write banks b, fold banks a
#define TILE_O(s,off) "s_waitcnt vmcnt(7)\n\t" \
  "v_mfma_f32_32x32x16_f16 v[48:63], %[" #s "], %[bf0], v[96:111]\n\t" \
  "v_mfma_f32_32x32x16_f16 v[80:95], %[" #s "], %[bf1], v[96:111]\n\t" \
  LD(s,off) FOLD_D0A FOLD_D1A
#define ZM(r)  "v_mov_b32 v" #r ", 0\n\t"
#define IM(r)  "v_mov_b32 v" #r ", 0x7f800000\n\t"   // +inf: min-identity

// Grid (16,16,2) = 512 blocks x 4 waves, 2 blocks/CU (launch_bounds(256,2)).
// R12: NB=2 -- each 1 KB A-tile load feeds TWO MFMAs (64 queries/wave).
// Halves wave count (2048) and L1 A-traffic (512->256 MB), the R11 binder.
// Ring depth 8 (vmcnt(7)); D banks: tile t's D folded at tile t+1; odd banks
// pre-init to +inf so the uniform loop's first fold is harmless.
__global__ __launch_bounds__(256, 2) void chamfer_mfma(
    const float* __restrict__ tpl, const float* __restrict__ src,
    const _Float16* __restrict__ arow, float* __restrict__ blocksum,
    float* __restrict__ out) {
    __shared__ float wsum[4];

    const int tid = threadIdx.x;
    const int wv = tid >> 6, lane = tid & 63;
    const int n = lane & 31, g = lane >> 5;           // B col / K-half group
    const int qb = blockIdx.x, batch = blockIdx.y, dir = blockIdx.z;

    const float* qpts = (dir == 0) ? src : tpl;       // dist1: query = source
    const _Float16* abase = arow + ((dir == 0) ? (size_t)0 : (size_t)65536 * 16)
                          + (size_t)batch * 4096 * 16;

    // Two B fragments (frag i -> query qb*256 + wv*64 + i*32 + n) + |p|^2.
    f16x8 bfr[2];
    float p2[2];
    #pragma unroll
    for (int i = 0; i < 2; ++i) {
        const int q = qb * 256 + wv * 64 + i * 32 + n;
        const float* p = qpts + (size_t)(batch * 4096 + q) * 3;
        float px = p[0], py = p[1], pz = p[2];
        p2[i] = fmaf(px, px, fmaf(py, py, pz * pz));
        _Float16 xh = (_Float16)px, yh = (_Float16)py, zh = (_Float16)pz;
        _Float16 xl = (_Float16)(px - (float)xh);
        _Float16 yl = (_Float16)(py - (float)yh);
        _Float16 zl = (_Float16)(pz - (float)zh);
        f16x8 b;
        if (g == 0) {
            b[0] = xh; b[1] = yh; b[2] = zh;
            b[3] = xh; b[4] = yh; b[5] = zh;
            b[6] = xl; b[7] = yl;
        } else {
            b[0] = zl; b[1] = (_Float16)1.0f; b[2] = (_Float16)1.0f;
            b[3] = (_Float16)0.0f; b[4] = (_Float16)0.0f; b[5] = (_Float16)0.0f;
            b[6] = (_Float16)0.0f; b[7] = (_Float16)0.0f;
        }
        bfr[i] = b;
    }

    int voff = n * 32 + g * 16;    // per-lane byte offset into A region
    int cnt = 16;                  // 16 iterations x 8 tiles = 128 tiles
    float acc0 = 1e30f, acc1 = 1e30f, acc2 = 1e30f, acc3 = 1e30f;
    f16x8 r0, r1, r2, r3, r4, r5, r6, r7;   // ring, allocator-assigned

    asm volatile(
        // zero-C pinned v[96:111] once; odd banks (v48-63, v80-95) to +inf
        ZM(96) ZM(97) ZM(98) ZM(99) ZM(100) ZM(101) ZM(102) ZM(103)
        ZM(104) ZM(105) ZM(106) ZM(107) ZM(108) ZM(109) ZM(110) ZM(111)
        IM(48) IM(49) IM(50) IM(51) IM(52) IM(53) IM(54) IM(55)
        IM(56) IM(57) IM(58) IM(59) IM(60) IM(61) IM(62) IM(63)
        IM(80) IM(81) IM(82) IM(83) IM(84) IM(85) IM(86) IM(87)
        IM(88) IM(89) IM(90) IM(91) IM(92) IM(93) IM(94) IM(95)
        // prime ring: tiles 0..7
        LD(r0,0) LD(r1,1024) LD(r2,2048) LD(r3,3072)
        "v_add_u32 %[voff], 0x1000, %[voff]\n\t"
        LD(r4,0) LD(r5,1024) LD(r6,2048) LD(r7,3072)
        "v_add_u32 %[voff], 0x1000, %[voff]\n\t"
        // steady loop: 8 tiles/iter; loads target tile+8 (last iter's 8 loads
        // land past the region -- never consumed, drained at the end)
        "L_cham_%=:\n\t"
        TILE_E(r0,0) TILE_O(r1,1024) TILE_E(r2,2048) TILE_O(r3,3072)
        "v_add_u32 %[voff], 0x1000, %[voff]\n\t"
        TILE_E(r4,0) TILE_O(r5,1024) TILE_E(r6,2048) TILE_O(r7,3072)
        "v_add_u32 %[voff], 0x1000, %[voff]\n\t"
        "s_sub_u32 %[cnt], %[cnt], 1\n\t"
        "s_cmp_lg_u32 %[cnt], 0\n\t"
        "s_cbranch_scc1 L_cham_%=\n\t"
        // tile 127 (odd) wrote banks b, not yet folded; MFMA drain then fold
        "s_nop 7\n\t" "s_nop 7\n\t" "s_nop 7\n\t"
        FOLD_D0B FOLD_D1B
        "s_waitcnt vmcnt(0)\n\t"   // drain overshoot loads before reg reuse
        : [r0]"=&v"(r0), [r1]"=&v"(r1), [r2]"=&v"(r2), [r3]"=&v"(r3),
          [r4]"=&v"(r4), [r5]"=&v"(r5), [r6]"=&v"(r6), [r7]"=&v"(r7),
          [voff]"+v"(voff), [cnt]"+s"(cnt),
          [acc0]"+v"(acc0), [acc1]"+v"(acc1), [acc2]"+v"(acc2), [acc3]"+v"(acc3)
        : [bf0]"v"(bfr[0]), [bf1]"v"(bfr[1]), [sb]"s"(abase)
        : "memory", "scc",
          "v32","v33","v34","v35","v36","v37","v38","v39",
          "v40","v41","v42","v43","v44","v45","v46","v47",
          "v48","v49","v50","v51","v52","v53","v54","v55",
          "v56","v57","v58","v59","v60","v61","v62","v63",
          "v64","v65","v66","v67","v68","v69","v70","v71",
          "v72","v73","v74","v75","v76","v77","v78","v79",
          "v80","v81","v82","v83","v84","v85","v86","v87",
          "v88","v89","v90","v91","v92","v93","v94","v95",
          "v96","v97","v98","v99","v100","v101","v102","v103",
          "v104","v105","v106","v107","v108","v109","v110","v111");

    // Per-frag: rows split across lane halves; fold, clamp, sqrt.
    float v0 = fminf(acc0, acc1);
    v0 = fminf(v0, __shfl_xor(v0, 32));
    float v1 = fminf(acc2, acc3);
    v1 = fminf(v1, __shfl_xor(v1, 32));
    float d0 = fmaxf(v0 + p2[0], 0.0f);                // == min of clamped
    float d1 = fmaxf(v1 + p2[1], 0.0f);
    float s = (sqrtf(d0) + sqrtf(d1)) * INV_CNT;
    if (g != 0) s = 0.0f;                              // count each query once
    #pragma unroll
    for (int off = 32; off > 0; off >>= 1) s += __shfl_down(s, off);
    if (lane == 0) wsum[wv] = s;
    __syncthreads();
    if (tid == 0) {
        float t = wsum[0] + wsum[1] + wsum[2] + wsum[3];
        if (blocksum) {
            int flat = (blockIdx.z * N_BATCH + blockIdx.y) * 16 + blockIdx.x;
            blocksum[flat] = t;                        // unique slot: no atomics
        } else {
            atomicAdd(out, t);                         // fallback (small ws)
        }
    }
}

// Reduce 512 block sums -> out[0]. Single block, no atomics.
__global__ __launch_bounds__(256) void final_kernel(
    const float* __restrict__ blocksum, float* __restrict__ out) {
    __shared__ float wsum[4];
    float s = 0.0f;
    #pragma unroll
    for (int j = 0; j < NBLK / 256; ++j)
        s += blocksum[j * 256 + threadIdx.x];
    #pragma unroll
    for (int off = 32; off > 0; off >>= 1) s += __shfl_down(s, off);
    if ((threadIdx.x & 63) == 0) wsum[threadIdx.x >> 6] = s;
    __syncthreads();
    if (threadIdx.x == 0) out[0] = wsum[0] + wsum[1] + wsum[2] + wsum[3];
}

extern "C" void kernel_launch(void* const* d_in, const int* in_sizes, int n_in,
                              void* d_out, int out_size, void* d_ws, size_t ws_size,
                              hipStream_t stream) {
    const float* tpl = (const float*)d_in[0];
    const float* src = (const float*)d_in[1];
    float* out = (float*)d_out;
    _Float16* arow = (_Float16*)d_ws;                  // 4 MB
    // main kernel's ring overshoots the A region by 8 KB: need slack too
    const bool roomy = ws_size >= AROW_BYTES + 8192 + NBLK * sizeof(float);
    float* blocksum = roomy ? (float*)((char*)d_ws + AROW_BYTES + 8192) : nullptr;

    hipLaunchKernelGGL(prep_kernel, dim3((2 * N_BATCH * N_PTS) / 256),
                       dim3(256), 0, stream, tpl, src, arow, out);
    dim3 grid(N_PTS / 256, N_BATCH, 2);                // (16, 16, 2) = 512 blocks
    hipLaunchKernelGGL(chamfer_mfma, grid, dim3(256), 0, stream,
                       tpl, src, arow, blocksum, out);
    if (roomy)
        hipLaunchKernelGGL(final_kernel, dim3(1), dim3(256), 0, stream,
                           blocksum, out);
}